// Round 5
// baseline (764.946 us; speedup 1.0000x reference)
//
#include <hip/hip_runtime.h>

constexpr int Bc = 32;     // batch
constexpr int Tc = 1000;   // time
constexpr int Vc = 1024;   // vocab
constexpr int Lc = 128;    // label length
constexpr int Sc = 2 * Lc + 1;  // 257 lattice states
constexpr int SP = 320;         // padded stride: 5 states/lane * 64 lanes
constexpr int WPB = 16;         // waves per block in ctc_alpha (co-location)
constexpr float NEGF = -1e30f;  // log-space -inf surrogate (reference NEG)
constexpr float L2E = 1.4426950408889634f;   // log2(e)
constexpr float LN2 = 0.6931471805599453f;   // ln(2)

#if __has_builtin(__builtin_amdgcn_exp2f)
#define EXP2F(x) __builtin_amdgcn_exp2f(x)
#else
#define EXP2F(x) exp2f(x)
#endif
#if __has_builtin(__builtin_amdgcn_logf)
#define LOG2F(x) __builtin_amdgcn_logf(x)
#else
#define LOG2F(x) log2f(x)
#endif
#if __has_builtin(__builtin_amdgcn_fmed3f)
#define MED3F(x, y, z) __builtin_amdgcn_fmed3f(x, y, z)
#else
#define MED3F(x, y, z) fmaxf(fminf(fmaxf(x, y), z), fminf(x, y))
#endif

// Interleaved lattice layout: position p = j*64 + lane holds state s = 5*lane + j.

// ---------------------------------------------------------------------------
// Kernel A: log-softmax + gather, one WAVE per (b,t) row. UNCHANGED from R4
// (control: structure-invariant ~185us across 3 rewrites; next round it is
// the top dispatch and we finally see its counters).
// ---------------------------------------------------------------------------
__global__ __launch_bounds__(256) void ctc_lse_gather(
    const float* __restrict__ hs, const int* __restrict__ ys,
    float* __restrict__ lpe) {
  const int wv = threadIdx.x >> 6;
  const int lane = threadIdx.x & 63;
  const int bt = blockIdx.x * 4 + wv;   // row index b*Tc + t
  const int b = bt / Tc;
  const float* row = hs + (size_t)bt * Vc;

  __shared__ float xs_all[4][Vc];
  float* xs = xs_all[wv];

  float4 v[4];
#pragma unroll
  for (int q = 0; q < 4; ++q) v[q] = reinterpret_cast<const float4*>(row)[lane + 64 * q];
#pragma unroll
  for (int q = 0; q < 4; ++q) { v[q].x *= L2E; v[q].y *= L2E; v[q].z *= L2E; v[q].w *= L2E; }

  float m = -3.4e38f;
#pragma unroll
  for (int q = 0; q < 4; ++q)
    m = fmaxf(m, fmaxf(fmaxf(v[q].x, v[q].y), fmaxf(v[q].z, v[q].w)));
#pragma unroll
  for (int off = 32; off; off >>= 1) m = fmaxf(m, __shfl_xor(m, off, 64));

  float sum = 0.f;
#pragma unroll
  for (int q = 0; q < 4; ++q)
    sum += EXP2F(v[q].x - m) + EXP2F(v[q].y - m) + EXP2F(v[q].z - m) + EXP2F(v[q].w - m);
#pragma unroll
  for (int off = 32; off; off >>= 1) sum += __shfl_xor(sum, off, 64);
  const float lse2 = m + LOG2F(sum);

#pragma unroll
  for (int q = 0; q < 4; ++q) reinterpret_cast<float4*>(xs)[lane + 64 * q] = v[q];
  __syncthreads();

  float* out = lpe + (size_t)bt * SP;
#pragma unroll
  for (int j = 0; j < 5; ++j) {
    const int s = 5 * lane + j;
    float val = NEGF;
    if (s < Sc) {
      const int lab = (s & 1) ? ys[b * Lc + (s >> 1)] : 0;
      val = xs[lab] - lse2;
    }
    out[j * 64 + lane] = val;
  }
}

// Sorted 3-way logaddexp in log2 domain: exp2 of the max term is exactly 1.
__device__ inline float lae3(float x, float y, float z) {
  const float M = fmaxf(fmaxf(x, y), z);
  const float md = MED3F(x, y, z);
  const float mn = fminf(fminf(x, y), z);
  const float s = 1.f + EXP2F(md - M) + EXP2F(mn - M);
  return M + LOG2F(s);
}

// ---------------------------------------------------------------------------
// Kernel B: CTC alpha recursion, log2 domain. CO-LOCATED: 2 blocks x 16 waves
// so 4 independent recursions share each SIMD — issue/latency of one wave is
// hidden by the other three (m114 co-scheduling). Inner math identical to R4.
// ---------------------------------------------------------------------------
__global__ __launch_bounds__(WPB * 64) void ctc_alpha(
    const float* __restrict__ lpe, const int* __restrict__ ys,
    const int* __restrict__ hlen, const int* __restrict__ ylen,
    float* __restrict__ lossb) {
  const int wv = threadIdx.x >> 6;
  const int lane = threadIdx.x & 63;
  const int b = blockIdx.x * WPB + wv;
  const float* pb = lpe + (size_t)b * Tc * SP;

  // skip-transition mask
  bool sk[5];
#pragma unroll
  for (int j = 0; j < 5; ++j) {
    const int s = 5 * lane + j;
    bool vv = false;
    if ((s & 1) && s >= 3 && s < Sc) {
      const int y1 = ys[b * Lc + (s >> 1)];
      const int y0 = ys[b * Lc + ((s - 2) >> 1)];
      vv = (y1 != y0);  // labels >=1, so y1 != blank always
    }
    sk[j] = vv;
  }

  // alpha at t=0: state 0 at pos 0, state 1 at pos 64 (interleaved layout)
  float a[5];
#pragma unroll
  for (int j = 0; j < 5; ++j) {
    const int s = 5 * lane + j;
    a[j] = (s == 0) ? pb[0] : ((s == 1) ? pb[64] : NEGF);
  }

  const int Te = min(hlen[b], Tc);

  auto step = [&](const float* lp) {
    float am1 = __shfl_up(a[4], 1, 64);  // alpha[s-1] for j=0
    float am2 = __shfl_up(a[3], 1, 64);  // alpha[s-2] for j=0
    if (lane == 0) { am1 = NEGF; am2 = NEGF; }
    const float n0 = lae3(a[0], am1, sk[0] ? am2 : NEGF) + lp[0];
    const float n1 = lae3(a[1], a[0], sk[1] ? am1 : NEGF) + lp[1];
    const float n2 = lae3(a[2], a[1], sk[2] ? a[0] : NEGF) + lp[2];
    const float n3 = lae3(a[3], a[2], sk[3] ? a[1] : NEGF) + lp[3];
    const float n4 = lae3(a[4], a[3], sk[4] ? a[2] : NEGF) + lp[4];
    a[0] = n0; a[1] = n1; a[2] = n2; a[3] = n3; a[4] = n4;
  };

  float bufA[8][5], bufB[8][5];
  auto load8A = [&](int trow) {
    const float* p = pb + (size_t)trow * SP + lane;
#pragma unroll
    for (int k = 0; k < 8; ++k)
#pragma unroll
      for (int j = 0; j < 5; ++j) bufA[k][j] = p[k * SP + j * 64];
  };
  auto load8B = [&](int trow) {
    const float* p = pb + (size_t)trow * SP + lane;
#pragma unroll
    for (int k = 0; k < 8; ++k)
#pragma unroll
      for (int j = 0; j < 5; ++j) bufB[k][j] = p[k * SP + j * 64];
  };

  int t = 1;
  if (t + 8 <= Te) load8A(t);
  while (t + 16 <= Te) {
    load8B(t + 8);
#pragma unroll
    for (int k = 0; k < 8; ++k) step(bufA[k]);
    t += 8;
    if (t + 16 <= Te) load8A(t + 8);
#pragma unroll
    for (int k = 0; k < 8; ++k) step(bufB[k]);
    t += 8;
  }
  if (t + 8 <= Te) {
#pragma unroll
    for (int k = 0; k < 8; ++k) step(bufA[k]);
    t += 8;
  }
  while (t < Te) {
    float lp[5];
#pragma unroll
    for (int j = 0; j < 5; ++j) lp[j] = pb[(size_t)t * SP + j * 64 + lane];
    step(lp);
    ++t;
  }

  // final: loss = -ln2 * logaddexp2(alpha[2L], alpha[2L-1]) / ylen
  __shared__ float ash[WPB][SP];
#pragma unroll
  for (int j = 0; j < 5; ++j) ash[wv][5 * lane + j] = a[j];
  __syncthreads();
  if (lane == 0) {
    const int yl = ylen[b];
    const float x = ash[wv][2 * yl];
    const float y = ash[wv][2 * yl - 1];
    const float M = fmaxf(x, y);
    const float ae2 = M + LOG2F(EXP2F(x - M) + EXP2F(y - M));
    lossb[b] = -(ae2 * LN2) / (float)yl;
  }
}

// ---------------------------------------------------------------------------
// Kernel C: mean over batch
// ---------------------------------------------------------------------------
__global__ __launch_bounds__(64) void ctc_final(
    const float* __restrict__ lossb, float* __restrict__ out) {
  const int lane = threadIdx.x;
  float v = (lane < Bc) ? lossb[lane] : 0.f;
#pragma unroll
  for (int off = 32; off; off >>= 1) v += __shfl_xor(v, off, 64);
  if (lane == 0) out[0] = v * (1.f / (float)Bc);
}

extern "C" void kernel_launch(void* const* d_in, const int* in_sizes, int n_in,
                              void* d_out, int out_size, void* d_ws, size_t ws_size,
                              hipStream_t stream) {
  const float* hs = (const float*)d_in[0];    // (B,T,V) fp32
  const int* hlen = (const int*)d_in[1];      // (B,)
  const int* ys = (const int*)d_in[2];        // (B,L)
  const int* ylen = (const int*)d_in[3];      // (B,)
  float* out = (float*)d_out;                 // scalar

  float* lpe = (float*)d_ws;                             // B*T*SP floats (~41 MB)
  float* lossb = lpe + (size_t)Bc * Tc * SP;             // B floats

  ctc_lse_gather<<<Bc * Tc / 4, 256, 0, stream>>>(hs, ys, lpe);
  ctc_alpha<<<Bc / WPB, WPB * 64, 0, stream>>>(lpe, ys, hlen, ylen, lossb);
  ctc_final<<<1, 64, 0, stream>>>(lossb, out);
}

// Round 6
// 338.146 us; speedup vs baseline: 2.2622x; 2.2622x over previous
//
#include <hip/hip_runtime.h>

constexpr int Bc = 32;     // batch
constexpr int Tc = 1000;   // time
constexpr int Vc = 1024;   // vocab
constexpr int Lc = 128;    // label length
constexpr int Sc = 2 * Lc + 1;  // 257 lattice states
constexpr int SP = 320;         // padded stride (positions 0..319)
constexpr float NEGF = -1e30f;  // log-space -inf surrogate (reference NEG)
constexpr float L2E = 1.4426950408889634f;   // log2(e)
constexpr float LN2 = 0.6931471805599453f;   // ln(2)

#if __has_builtin(__builtin_amdgcn_exp2f)
#define EXP2F(x) __builtin_amdgcn_exp2f(x)
#else
#define EXP2F(x) exp2f(x)
#endif
#if __has_builtin(__builtin_amdgcn_logf)
#define LOG2F(x) __builtin_amdgcn_logf(x)
#else
#define LOG2F(x) log2f(x)
#endif
#if __has_builtin(__builtin_amdgcn_fmed3f)
#define MED3F(x, y, z) __builtin_amdgcn_fmed3f(x, y, z)
#else
#define MED3F(x, y, z) fmaxf(fminf(fmaxf(x, y), z), fminf(x, y))
#endif

// Parity-uniform layout: lane l holds states s = 4l+j for slots j=0..3
// (slot parity == j parity, wave-uniform!), plus state 256 in slot 4 of
// lane 63. Storage position: p = j*64 + lane (j<4), p = 256+lane (slot 4).
// Slots 0,2,4 are blank states (2-term logaddexp); slots 1,3 are label
// states (3-term). Only ONE cross-lane value needed per step: state 4l-1
// = lane l-1 slot 3 (serves as slot0's s-1 AND slot1's s-2).

// ---------------------------------------------------------------------------
// Kernel A: log-softmax + gather, one WAVE per (b,t) row. Same traffic and
// instruction mix as the R4 control; only the gather mapping changed to the
// parity-uniform layout.
// ---------------------------------------------------------------------------
__global__ __launch_bounds__(256) void ctc_lse_gather(
    const float* __restrict__ hs, const int* __restrict__ ys,
    float* __restrict__ lpe) {
  const int wv = threadIdx.x >> 6;
  const int lane = threadIdx.x & 63;
  const int bt = blockIdx.x * 4 + wv;   // row index b*Tc + t
  const int b = bt / Tc;
  const float* row = hs + (size_t)bt * Vc;

  __shared__ float xs_all[4][Vc];
  float* xs = xs_all[wv];

  float4 v[4];
#pragma unroll
  for (int q = 0; q < 4; ++q) v[q] = reinterpret_cast<const float4*>(row)[lane + 64 * q];
#pragma unroll
  for (int q = 0; q < 4; ++q) { v[q].x *= L2E; v[q].y *= L2E; v[q].z *= L2E; v[q].w *= L2E; }

  float m = -3.4e38f;
#pragma unroll
  for (int q = 0; q < 4; ++q)
    m = fmaxf(m, fmaxf(fmaxf(v[q].x, v[q].y), fmaxf(v[q].z, v[q].w)));
#pragma unroll
  for (int off = 32; off; off >>= 1) m = fmaxf(m, __shfl_xor(m, off, 64));

  float sum = 0.f;
#pragma unroll
  for (int q = 0; q < 4; ++q)
    sum += EXP2F(v[q].x - m) + EXP2F(v[q].y - m) + EXP2F(v[q].z - m) + EXP2F(v[q].w - m);
#pragma unroll
  for (int off = 32; off; off >>= 1) sum += __shfl_xor(sum, off, 64);
  const float lse2 = m + LOG2F(sum);

#pragma unroll
  for (int q = 0; q < 4; ++q) reinterpret_cast<float4*>(xs)[lane + 64 * q] = v[q];
  __syncthreads();

  float* out = lpe + (size_t)bt * SP;
#pragma unroll
  for (int j = 0; j < 4; ++j) {     // states s = 4*lane + j  (0..255)
    const int s = 4 * lane + j;
    const int lab = (s & 1) ? ys[b * Lc + (s >> 1)] : 0;
    out[j * 64 + lane] = xs[lab] - lse2;   // coalesced 256B store per j
  }
  // slot 4: state 256 (last blank) on lane 63, NEGF padding elsewhere
  out[256 + lane] = (lane == 63) ? (xs[0] - lse2) : NEGF;
}

// 2-term logaddexp, log2 domain (exp2 of max term is exactly 1).
__device__ inline float lae2(float x, float y) {
  const float M = fmaxf(x, y);
  const float mn = fminf(x, y);
  return M + LOG2F(1.f + EXP2F(mn - M));
}
// Sorted 3-term logaddexp, log2 domain.
__device__ inline float lae3(float x, float y, float z) {
  const float M = fmaxf(fmaxf(x, y), z);
  const float md = MED3F(x, y, z);
  const float mn = fminf(fminf(x, y), z);
  return M + LOG2F(1.f + EXP2F(md - M) + EXP2F(mn - M));
}

// ---------------------------------------------------------------------------
// Kernel B: CTC alpha recursion, log2 domain, ONE WAVE PER CU (max spread —
// 32 chains < 256 CUs, so co-location can only serialize; R5 post-mortem).
// Parity-uniform slots: 12 trans + ~34 VALU + 1 shuffle per step.
// ---------------------------------------------------------------------------
__global__ __launch_bounds__(64) void ctc_alpha(
    const float* __restrict__ lpe, const int* __restrict__ ys,
    const int* __restrict__ hlen, const int* __restrict__ ylen,
    float* __restrict__ lossb) {
  const int b = blockIdx.x;
  const int lane = threadIdx.x;
  const float* pb = lpe + (size_t)b * Tc * SP;

  // skip masks for the two label slots (wave-uniform slot parity):
  // slot1: s=4l+1 (needs l>=1 for s>=3): labels ys[2l-1] vs ys[2l]
  // slot3: s=4l+3: labels ys[2l] vs ys[2l+1]
  const int* yb = ys + b * Lc;
  const bool sk1 = (lane >= 1) && (yb[2 * lane - 1] != yb[2 * lane]);
  const bool sk3 = (yb[2 * lane] != yb[2 * lane + 1]);

  // alpha at t=0: state 0 (lane0 slot0) and state 1 (lane0 slot1)
  float a[5];
  a[0] = (lane == 0) ? pb[0] : NEGF;
  a[1] = (lane == 0) ? pb[64] : NEGF;
  a[2] = NEGF; a[3] = NEGF; a[4] = NEGF;

  const int Te = min(hlen[b], Tc);

  auto step = [&](const float* lp) {
    float am = __shfl_up(a[3], 1, 64);   // state 4l-1 from lane l-1
    if (lane == 0) am = NEGF;
    const float n0 = lae2(a[0], am) + lp[0];                      // blank
    const float n1 = lae3(a[1], a[0], sk1 ? am : NEGF) + lp[1];   // label
    const float n2 = lae2(a[2], a[1]) + lp[2];                    // blank
    const float n3 = lae3(a[3], a[2], sk3 ? a[1] : NEGF) + lp[3]; // label
    const float n4 = lae2(a[4], a[3]) + lp[4];                    // last blank
    a[0] = n0; a[1] = n1; a[2] = n2; a[3] = n3; a[4] = n4;
  };

  float bufA[8][5], bufB[8][5];
  auto load8A = [&](int trow) {
    const float* p = pb + (size_t)trow * SP + lane;
#pragma unroll
    for (int k = 0; k < 8; ++k)
#pragma unroll
      for (int j = 0; j < 5; ++j) bufA[k][j] = p[k * SP + j * 64];
  };
  auto load8B = [&](int trow) {
    const float* p = pb + (size_t)trow * SP + lane;
#pragma unroll
    for (int k = 0; k < 8; ++k)
#pragma unroll
      for (int j = 0; j < 5; ++j) bufB[k][j] = p[k * SP + j * 64];
  };

  int t = 1;
  if (t + 8 <= Te) load8A(t);
  while (t + 16 <= Te) {
    load8B(t + 8);
#pragma unroll
    for (int k = 0; k < 8; ++k) step(bufA[k]);
    t += 8;
    if (t + 16 <= Te) load8A(t + 8);
#pragma unroll
    for (int k = 0; k < 8; ++k) step(bufB[k]);
    t += 8;
  }
  if (t + 8 <= Te) {
#pragma unroll
    for (int k = 0; k < 8; ++k) step(bufA[k]);
    t += 8;
  }
  while (t < Te) {
    float lp[5];
#pragma unroll
    for (int j = 0; j < 5; ++j) lp[j] = pb[(size_t)t * SP + j * 64 + lane];
    step(lp);
    ++t;
  }

  // final: loss = -ln2 * logaddexp2(alpha[2L], alpha[2L-1]) / ylen
  __shared__ float ash[SP];
#pragma unroll
  for (int j = 0; j < 4; ++j) ash[4 * lane + j] = a[j];
  if (lane == 63) ash[256] = a[4];
  __syncthreads();
  if (lane == 0) {
    const int yl = ylen[b];
    const float x = ash[2 * yl];
    const float y = ash[2 * yl - 1];
    const float M = fmaxf(x, y);
    const float ae2 = M + LOG2F(EXP2F(x - M) + EXP2F(y - M));
    lossb[b] = -(ae2 * LN2) / (float)yl;
  }
}

// ---------------------------------------------------------------------------
// Kernel C: mean over batch
// ---------------------------------------------------------------------------
__global__ __launch_bounds__(64) void ctc_final(
    const float* __restrict__ lossb, float* __restrict__ out) {
  const int lane = threadIdx.x;
  float v = (lane < Bc) ? lossb[lane] : 0.f;
#pragma unroll
  for (int off = 32; off; off >>= 1) v += __shfl_xor(v, off, 64);
  if (lane == 0) out[0] = v * (1.f / (float)Bc);
}

extern "C" void kernel_launch(void* const* d_in, const int* in_sizes, int n_in,
                              void* d_out, int out_size, void* d_ws, size_t ws_size,
                              hipStream_t stream) {
  const float* hs = (const float*)d_in[0];    // (B,T,V) fp32
  const int* hlen = (const int*)d_in[1];      // (B,)
  const int* ys = (const int*)d_in[2];        // (B,L)
  const int* ylen = (const int*)d_in[3];      // (B,)
  float* out = (float*)d_out;                 // scalar

  float* lpe = (float*)d_ws;                             // B*T*SP floats (~41 MB)
  float* lossb = lpe + (size_t)Bc * Tc * SP;             // B floats

  ctc_lse_gather<<<Bc * Tc / 4, 256, 0, stream>>>(hs, ys, lpe);
  ctc_alpha<<<Bc, 64, 0, stream>>>(lpe, ys, hlen, ylen, lossb);
  ctc_final<<<1, 64, 0, stream>>>(lossb, out);
}

// Round 8
// 305.964 us; speedup vs baseline: 2.5001x; 1.1052x over previous
//
#include <hip/hip_runtime.h>
#include <math.h>

constexpr int Bc = 32;     // batch
constexpr int Tc = 1000;   // time
constexpr int Vc = 1024;   // vocab
constexpr int Lc = 128;    // label length
constexpr int Sc = 2 * Lc + 1;  // 257 lattice states
constexpr int SP = 320;         // padded stride (positions 0..319)
constexpr float NEGF = -1e30f;
constexpr float L2E = 1.4426950408889634f;   // log2(e)
constexpr float LN2 = 0.6931471805599453f;   // ln(2)
constexpr int ENEG = -(1 << 24);             // sentinel exponent: "no mass"

#if __has_builtin(__builtin_amdgcn_exp2f)
#define EXP2F(x) __builtin_amdgcn_exp2f(x)
#else
#define EXP2F(x) exp2f(x)
#endif
#if __has_builtin(__builtin_amdgcn_logf)
#define LOG2F(x) __builtin_amdgcn_logf(x)
#else
#define LOG2F(x) log2f(x)
#endif
#if __has_builtin(__builtin_amdgcn_ldexpf)
#define LDEXPF(x, e) __builtin_amdgcn_ldexpf(x, e)
#else
#define LDEXPF(x, e) ldexpf(x, e)
#endif
#if __has_builtin(__builtin_amdgcn_frexp_expf)
#define FREXPE(x) __builtin_amdgcn_frexp_expf(x)
#else
__device__ inline int FREXPE(float x) { int e; (void)frexpf(x, &e); return e; }
#endif

// Parity-uniform layout: lane l holds states s = 4l+j (slots j=0..3), plus
// state 256 in slot 4 of lane 63. Position: p = j*64 + lane (j<4), 256+lane
// (slot 4). Slots 0,2,4 = blanks; 1,3 = labels. One cross-lane value per
// step: state 4l-1 = lane l-1 slot 3. Values are LINEAR probabilities.

// ---------------------------------------------------------------------------
// Kernel A: log-softmax + gather, one WAVE per (b,t) row; stores LINEAR
// p = exp2(x - lse). Padding slots store 0. (Unchanged from R7 — control.)
// ---------------------------------------------------------------------------
__global__ __launch_bounds__(256) void ctc_lse_gather(
    const float* __restrict__ hs, const int* __restrict__ ys,
    float* __restrict__ lpe) {
  const int wv = threadIdx.x >> 6;
  const int lane = threadIdx.x & 63;
  const int bt = blockIdx.x * 4 + wv;   // row index b*Tc + t
  const int b = bt / Tc;
  const float* row = hs + (size_t)bt * Vc;

  __shared__ float xs_all[4][Vc];
  float* xs = xs_all[wv];

  float4 v[4];
#pragma unroll
  for (int q = 0; q < 4; ++q) v[q] = reinterpret_cast<const float4*>(row)[lane + 64 * q];
#pragma unroll
  for (int q = 0; q < 4; ++q) { v[q].x *= L2E; v[q].y *= L2E; v[q].z *= L2E; v[q].w *= L2E; }

  float m = -3.4e38f;
#pragma unroll
  for (int q = 0; q < 4; ++q)
    m = fmaxf(m, fmaxf(fmaxf(v[q].x, v[q].y), fmaxf(v[q].z, v[q].w)));
#pragma unroll
  for (int off = 32; off; off >>= 1) m = fmaxf(m, __shfl_xor(m, off, 64));

  float sum = 0.f;
#pragma unroll
  for (int q = 0; q < 4; ++q)
    sum += EXP2F(v[q].x - m) + EXP2F(v[q].y - m) + EXP2F(v[q].z - m) + EXP2F(v[q].w - m);
#pragma unroll
  for (int off = 32; off; off >>= 1) sum += __shfl_xor(sum, off, 64);
  const float lse2 = m + LOG2F(sum);

#pragma unroll
  for (int q = 0; q < 4; ++q) reinterpret_cast<float4*>(xs)[lane + 64 * q] = v[q];
  __syncthreads();

  float* out = lpe + (size_t)bt * SP;
#pragma unroll
  for (int j = 0; j < 4; ++j) {     // states s = 4*lane + j (0..255)
    const int s = 4 * lane + j;
    const int lab = (s & 1) ? ys[b * Lc + (s >> 1)] : 0;
    out[j * 64 + lane] = EXP2F(xs[lab] - lse2);   // linear prob
  }
  // slot 4: state 256 (last blank) on lane 63, 0 elsewhere
  out[256 + lane] = (lane == 63) ? EXP2F(xs[0] - lse2) : 0.f;
}

// ---------------------------------------------------------------------------
// Kernel B: CTC alpha, LINEAR domain with PER-LANE integer exponent.
// true_alpha[slot j of lane l] = m[j] * 2^E(l). Zero-mass lanes carry the
// ENEG sentinel so they never dominate the scale reconcile (R7 post-mortem:
// stale E=0 on empty lanes flushed all incoming mass to zero).
// Zero transcendentals per step; one wave per CU.
// ---------------------------------------------------------------------------
__global__ __launch_bounds__(64) void ctc_alpha(
    const float* __restrict__ lpe, const int* __restrict__ ys,
    const int* __restrict__ hlen, const int* __restrict__ ylen,
    float* __restrict__ lossb) {
  const int b = blockIdx.x;
  const int lane = threadIdx.x;
  const float* pb = lpe + (size_t)b * Tc * SP;
  const int* yb = ys + b * Lc;

  // skip factors (wave-uniform slot parity): slot1: s=4l+1 (needs l>=1);
  // slot3: s=4l+3.
  const float sk1 = (lane >= 1 && yb[2 * lane - 1] != yb[2 * lane]) ? 1.f : 0.f;
  const float sk3 = (yb[2 * lane] != yb[2 * lane + 1]) ? 1.f : 0.f;

  // t=0: state 0 (lane0 slot0), state 1 (lane0 slot1); linear probs
  float m0 = (lane == 0) ? pb[0] : 0.f;
  float m1 = (lane == 0) ? pb[64] : 0.f;
  float m2 = 0.f, m3 = 0.f, m4 = 0.f;
  int E = (lane == 0) ? 0 : ENEG;     // sentinel: no mass on this lane yet

  const int Te = min(hlen[b], Tc);

  auto step = [&](const float* p) {
    float msh = __shfl_up(m3, 1, 64);   // state 4l-1 mantissa from lane l-1
    int Esh = __shfl_up(E, 1, 64);      // and its exponent
    if (lane == 0) { msh = 0.f; Esh = ENEG; }
    const int Et = max(E, Esh);         // ENEG iff neither side has mass
    const int dm = E - Et, dsh = Esh - Et;   // both <= 0: shrink-only, safe
    const float am = LDEXPF(msh, dsh);
    const float a0 = LDEXPF(m0, dm);
    const float a1 = LDEXPF(m1, dm);
    const float a2 = LDEXPF(m2, dm);
    const float a3 = LDEXPF(m3, dm);
    const float a4 = LDEXPF(m4, dm);
    const float n0 = (a0 + am) * p[0];                 // blank
    const float n1 = fmaf(sk1, am, a1 + a0) * p[1];    // label
    const float n2 = (a2 + a1) * p[2];                 // blank
    const float n3 = fmaf(sk3, a1, a3 + a2) * p[3];    // label
    const float n4 = (a4 + a3) * p[4];                 // last blank
    // exact per-lane renorm: keep max mantissa in [0.5, 1); zero mass -> ENEG
    const float mx = fmaxf(fmaxf(fmaxf(n0, n1), fmaxf(n2, n3)), n4);
    const int e = FREXPE(mx);           // 0 if mx == 0
    E = (mx > 0.f) ? (Et + e) : ENEG;
    m0 = LDEXPF(n0, -e);
    m1 = LDEXPF(n1, -e);
    m2 = LDEXPF(n2, -e);
    m3 = LDEXPF(n3, -e);
    m4 = LDEXPF(n4, -e);
  };

  float bufA[8][5], bufB[8][5];
  auto load8A = [&](int trow) {
    const float* p = pb + (size_t)trow * SP + lane;
#pragma unroll
    for (int k = 0; k < 8; ++k)
#pragma unroll
      for (int j = 0; j < 5; ++j) bufA[k][j] = p[k * SP + j * 64];
  };
  auto load8B = [&](int trow) {
    const float* p = pb + (size_t)trow * SP + lane;
#pragma unroll
    for (int k = 0; k < 8; ++k)
#pragma unroll
      for (int j = 0; j < 5; ++j) bufB[k][j] = p[k * SP + j * 64];
  };

  int t = 1;
  if (t + 8 <= Te) load8A(t);
  while (t + 16 <= Te) {
    load8B(t + 8);
#pragma unroll
    for (int k = 0; k < 8; ++k) step(bufA[k]);
    t += 8;
    if (t + 16 <= Te) load8A(t + 8);
#pragma unroll
    for (int k = 0; k < 8; ++k) step(bufB[k]);
    t += 8;
  }
  if (t + 8 <= Te) {
#pragma unroll
    for (int k = 0; k < 8; ++k) step(bufA[k]);
    t += 8;
  }
  while (t < Te) {
    float lp[5];
#pragma unroll
    for (int j = 0; j < 5; ++j) lp[j] = pb[(size_t)t * SP + j * 64 + lane];
    step(lp);
    ++t;
  }

  // final: loss = -ln2 * log2(alpha[2L] + alpha[2L-1]) / ylen, scales exact
  __shared__ float msm[SP];
  __shared__ int esm[64];
#pragma unroll
  for (int j = 0; j < 4; ++j) msm[4 * lane + j] = (j == 0 ? m0 : j == 1 ? m1 : j == 2 ? m2 : m3);
  if (lane == 63) msm[256] = m4;
  esm[lane] = E;
  __syncthreads();
  if (lane == 0) {
    const int yl = ylen[b];
    const int s1 = 2 * yl, s0 = 2 * yl - 1;
    const int l1 = (s1 == 256) ? 63 : (s1 >> 2);
    const int l0 = s0 >> 2;
    const float vx = msm[s1]; const int ex = esm[l1];
    const float vy = msm[s0]; const int ey = esm[l0];
    const int Em = max(ex, ey);
    const float r = LDEXPF(vx, ex - Em) + LDEXPF(vy, ey - Em);
    const float ae2 = (r > 0.f) ? (LOG2F(r) + (float)Em) : NEGF;
    lossb[b] = -(ae2 * LN2) / (float)yl;
  }
}

// ---------------------------------------------------------------------------
// Kernel C: mean over batch
// ---------------------------------------------------------------------------
__global__ __launch_bounds__(64) void ctc_final(
    const float* __restrict__ lossb, float* __restrict__ out) {
  const int lane = threadIdx.x;
  float v = (lane < Bc) ? lossb[lane] : 0.f;
#pragma unroll
  for (int off = 32; off; off >>= 1) v += __shfl_xor(v, off, 64);
  if (lane == 0) out[0] = v * (1.f / (float)Bc);
}

extern "C" void kernel_launch(void* const* d_in, const int* in_sizes, int n_in,
                              void* d_out, int out_size, void* d_ws, size_t ws_size,
                              hipStream_t stream) {
  const float* hs = (const float*)d_in[0];    // (B,T,V) fp32
  const int* hlen = (const int*)d_in[1];      // (B,)
  const int* ys = (const int*)d_in[2];        // (B,L)
  const int* ylen = (const int*)d_in[3];      // (B,)
  float* out = (float*)d_out;                 // scalar

  float* lpe = (float*)d_ws;                             // B*T*SP floats (~41 MB)
  float* lossb = lpe + (size_t)Bc * Tc * SP;             // B floats

  ctc_lse_gather<<<Bc * Tc / 4, 256, 0, stream>>>(hs, ys, lpe);
  ctc_alpha<<<Bc, 64, 0, stream>>>(lpe, ys, hlen, ylen, lossb);
  ctc_final<<<1, 64, 0, stream>>>(lossb, out);
}